// Round 7
// baseline (319.339 us; speedup 1.0000x reference)
//
#include <hip/hip_runtime.h>

typedef unsigned short u16;
typedef unsigned int u32;
typedef short bf16x8 __attribute__((ext_vector_type(8)));
typedef float f32x4 __attribute__((ext_vector_type(4)));

#define LQ_ 21760
#define LIN_ 21760
#define CDIM 256
#define MROWS (2 * LQ_)  // 43520

__device__ __forceinline__ u16 f2bf(float f) {
  u32 u;
  __builtin_memcpy(&u, &f, 4);
  u32 r = (u + 0x7fffu + ((u >> 16) & 1u)) >> 16;
  return (u16)r;
}
__device__ __forceinline__ u32 pack_bf16_rne(float a, float b) {
  return (u32)f2bf(a) | ((u32)f2bf(b) << 16);
}
__device__ __forceinline__ float bflo(u32 u) {
  u32 v = u << 16;
  float f;
  __builtin_memcpy(&f, &v, 4);
  return f;
}
__device__ __forceinline__ float bfhi(u32 u) {
  u32 v = u & 0xffff0000u;
  float f;
  __builtin_memcpy(&f, &v, 4);
  return f;
}
// async global->LDS, 16 B per lane; lds dest = wave-uniform base + lane*16
__device__ __forceinline__ void ldst16(const u16* g, u16* l) {
  __builtin_amdgcn_global_load_lds((const __attribute__((address_space(1))) void*)g,
                                   (__attribute__((address_space(3))) void*)l, 16, 0, 0);
}

// ---------- weight pre-conversion to bf16 fragment-chunk layout ----------
// chunkIdx = ks*(N/4) + (n>>4)*4 + ((k>>3)&3); element (n&15)*8 + (k&7).
__device__ __forceinline__ void conv_one(const float* W0, const float* W1, u16* Wf,
                                         int N, int split, int blk, int t) {
  const int tid = blk * 256 + t;
  if (tid >= N * 32) return;
  const int n = tid >> 5, kcg = tid & 31;
  float w[8];
#pragma unroll
  for (int j = 0; j < 8; ++j) {
    const int k = kcg * 8 + j;
    w[j] = (n < split) ? W0[(size_t)k * split + n]
                       : W1[(size_t)k * (N - split) + (n - split)];
  }
  uint4 pk;
  pk.x = pack_bf16_rne(w[0], w[1]);
  pk.y = pack_bf16_rne(w[2], w[3]);
  pk.z = pack_bf16_rne(w[4], w[5]);
  pk.w = pack_bf16_rne(w[6], w[7]);
  const int ks = kcg >> 2, kcr = kcg & 3, c = n >> 4;
  const int chunk = ks * (N / 4) + c * 4 + kcr;
  *(uint4*)(Wf + (size_t)chunk * 128 + (n & 15) * 8) = pk;
}

__global__ __launch_bounds__(256) void conv_all(
    const float* __restrict__ Wv, const float* __restrict__ Wof,
    const float* __restrict__ Wa, const float* __restrict__ Wo,
    const float* __restrict__ bof, const float* __restrict__ ba,
    u16* __restrict__ WfV, u16* __restrict__ WfC, u16* __restrict__ WfO,
    float* __restrict__ bcat) {
  const int b = blockIdx.x, t = threadIdx.x;
  if (b < 32) {
    conv_one(Wv, Wv, WfV, 256, 256, b, t);
  } else if (b < 80) {
    conv_one(Wof, Wa, WfC, 384, 256, b - 32, t);
  } else if (b < 112) {
    conv_one(Wo, Wo, WfO, 256, 256, b - 80, t);
  } else {
    const int i = (b - 112) * 256 + t;
    if (i < 384) bcat[i] = (i < 256) ? bof[i] : ba[i - 256];
  }
}

// ---------- activation pre-conversion: fp32 row-major -> bf16 frag-tile ----------
// tile (rb=row>>7, ks=k>>5) at (rb*8+ks)*4096; within: chunk c2=((row&127)>>4)*4
// + ((k&31)>>3), subrow row&15. Linear uint4 j: tile=j>>9, c2=(j>>4)&31, sr=j&15.
__global__ __launch_bounds__(256) void conv_act(const float* __restrict__ Aq,
                                                const float* __restrict__ Ai,
                                                u16* __restrict__ Qf,
                                                u16* __restrict__ If) {
  const int i = blockIdx.x * 256 + threadIdx.x;
  const int n4 = MROWS * 32;
  const float* src;
  u16* dst;
  int j;
  if (i < n4) {
    src = Aq;
    dst = Qf;
    j = i;
  } else {
    src = Ai;
    dst = If;
    j = i - n4;
  }
  const int tile = j >> 9;
  const int c2 = (j >> 4) & 31;
  const int sr = j & 15;
  const int row = (tile >> 3) * 128 + (c2 >> 2) * 16 + sr;
  const int kc = (tile & 7) * 32 + (c2 & 3) * 8;
  const float4 f0 = *(const float4*)(src + (size_t)row * 256 + kc);
  const float4 f1 = *(const float4*)(src + (size_t)row * 256 + kc + 4);
  uint4 pk;
  pk.x = pack_bf16_rne(f0.x, f0.y);
  pk.y = pack_bf16_rne(f0.z, f0.w);
  pk.z = pack_bf16_rne(f1.x, f1.y);
  pk.w = pack_bf16_rne(f1.z, f1.w);
  *(uint4*)(dst + (size_t)j * 8) = pk;
}

// ---------- GEMM cores: A (frag-tile bf16) @ Wf + bias ----------
// 128x128 tile, 4 waves 2x2, BK=32; staging = 4 async 16-B lds loads/thread.

// GEMM 1: value = If @ WfV + bv -> bf16 row-major
__global__ __launch_bounds__(256) void gemm_value(
    const u16* __restrict__ Af, const u16* __restrict__ Wf,
    const float* __restrict__ bias, u16* __restrict__ out) {
  __shared__ u16 sA[4096];
  __shared__ u16 sB[4096];
  const int rb = blockIdx.x >> 1, cb = blockIdx.x & 1;
  const int t = threadIdx.x, l = t & 63, wv = t >> 6;
  const int wr = wv >> 1, wc = wv & 1;
  const int fq = l >> 4, fr = l & 15;
  f32x4 acc[4][4];
#pragma unroll
  for (int r = 0; r < 4; ++r)
#pragma unroll
    for (int c = 0; c < 4; ++c) acc[r][c] = f32x4{0.f, 0.f, 0.f, 0.f};
  for (int ks = 0; ks < 8; ++ks) {
    __syncthreads();
    const u16* ga = Af + ((size_t)(rb * 8 + ks)) * 4096 + wv * 1024 + l * 8;
    u16* la = sA + wv * 1024;
    ldst16(ga, la);
    ldst16(ga + 512, la + 512);
    const u16* gb = Wf + ((size_t)(ks * 64 + cb * 32)) * 128 + wv * 1024 + l * 8;
    u16* lb = sB + wv * 1024;
    ldst16(gb, lb);
    ldst16(gb + 512, lb + 512);
    __syncthreads();
    bf16x8 af[4];
#pragma unroll
    for (int r = 0; r < 4; ++r)
      af[r] = *(const bf16x8*)(sA + ((wr * 4 + r) * 4 + fq) * 128 + fr * 8);
#pragma unroll
    for (int c = 0; c < 4; ++c) {
      const bf16x8 bf = *(const bf16x8*)(sB + ((wc * 4 + c) * 4 + fq) * 128 + fr * 8);
#pragma unroll
      for (int r = 0; r < 4; ++r)
        acc[r][c] = __builtin_amdgcn_mfma_f32_16x16x32_bf16(af[r], bf, acc[r][c], 0, 0, 0);
    }
  }
  const int rq = fq * 4;
#pragma unroll
  for (int c = 0; c < 4; ++c) {
    const int col = cb * 128 + wc * 64 + c * 16 + fr;
    const float bz = bias[col];
#pragma unroll
    for (int r = 0; r < 4; ++r) {
      const int row0 = rb * 128 + wr * 64 + r * 16 + rq;
#pragma unroll
      for (int g = 0; g < 4; ++g)
        out[(size_t)(row0 + g) * 256 + col] = f2bf(acc[r][c][g] + bz);
    }
  }
}

// GEMM 2: [off|attn] = Qf @ WfC + bcat -> f32 split, N=384
__global__ __launch_bounds__(256) void gemm_qc(
    const u16* __restrict__ Af, const u16* __restrict__ Wf,
    const float* __restrict__ bias, float* __restrict__ outO,
    float* __restrict__ outA) {
  __shared__ u16 sA[4096];
  __shared__ u16 sB[4096];
  const int rb = blockIdx.x / 3, cb = blockIdx.x % 3;
  const int t = threadIdx.x, l = t & 63, wv = t >> 6;
  const int wr = wv >> 1, wc = wv & 1;
  const int fq = l >> 4, fr = l & 15;
  f32x4 acc[4][4];
#pragma unroll
  for (int r = 0; r < 4; ++r)
#pragma unroll
    for (int c = 0; c < 4; ++c) acc[r][c] = f32x4{0.f, 0.f, 0.f, 0.f};
  for (int ks = 0; ks < 8; ++ks) {
    __syncthreads();
    const u16* ga = Af + ((size_t)(rb * 8 + ks)) * 4096 + wv * 1024 + l * 8;
    u16* la = sA + wv * 1024;
    ldst16(ga, la);
    ldst16(ga + 512, la + 512);
    const u16* gb = Wf + ((size_t)(ks * 96 + cb * 32)) * 128 + wv * 1024 + l * 8;
    u16* lb = sB + wv * 1024;
    ldst16(gb, lb);
    ldst16(gb + 512, lb + 512);
    __syncthreads();
    bf16x8 af[4];
#pragma unroll
    for (int r = 0; r < 4; ++r)
      af[r] = *(const bf16x8*)(sA + ((wr * 4 + r) * 4 + fq) * 128 + fr * 8);
#pragma unroll
    for (int c = 0; c < 4; ++c) {
      const bf16x8 bf = *(const bf16x8*)(sB + ((wc * 4 + c) * 4 + fq) * 128 + fr * 8);
#pragma unroll
      for (int r = 0; r < 4; ++r)
        acc[r][c] = __builtin_amdgcn_mfma_f32_16x16x32_bf16(af[r], bf, acc[r][c], 0, 0, 0);
    }
  }
  const int rq = fq * 4;
#pragma unroll
  for (int c = 0; c < 4; ++c) {
    const int col = cb * 128 + wc * 64 + c * 16 + fr;
    const float bz = bias[col];
#pragma unroll
    for (int r = 0; r < 4; ++r) {
      const int row0 = rb * 128 + wr * 64 + r * 16 + rq;
#pragma unroll
      for (int g = 0; g < 4; ++g) {
        const float v = acc[r][c][g] + bz;
        if (col < 256)
          outO[(size_t)(row0 + g) * 256 + col] = v;
        else
          outA[(size_t)(row0 + g) * 128 + (col - 256)] = v;
      }
    }
  }
}

// GEMM 3: out = samp(frag-tile bf16) @ WfO + bo -> f32
__global__ __launch_bounds__(256) void gemm_out(
    const u16* __restrict__ Af, const u16* __restrict__ Wf,
    const float* __restrict__ bias, float* __restrict__ out) {
  __shared__ u16 sA[4096];
  __shared__ u16 sB[4096];
  const int rb = blockIdx.x >> 1, cb = blockIdx.x & 1;
  const int t = threadIdx.x, l = t & 63, wv = t >> 6;
  const int wr = wv >> 1, wc = wv & 1;
  const int fq = l >> 4, fr = l & 15;
  f32x4 acc[4][4];
#pragma unroll
  for (int r = 0; r < 4; ++r)
#pragma unroll
    for (int c = 0; c < 4; ++c) acc[r][c] = f32x4{0.f, 0.f, 0.f, 0.f};
  for (int ks = 0; ks < 8; ++ks) {
    __syncthreads();
    const u16* ga = Af + ((size_t)(rb * 8 + ks)) * 4096 + wv * 1024 + l * 8;
    u16* la = sA + wv * 1024;
    ldst16(ga, la);
    ldst16(ga + 512, la + 512);
    const u16* gb = Wf + ((size_t)(ks * 64 + cb * 32)) * 128 + wv * 1024 + l * 8;
    u16* lb = sB + wv * 1024;
    ldst16(gb, lb);
    ldst16(gb + 512, lb + 512);
    __syncthreads();
    bf16x8 af[4];
#pragma unroll
    for (int r = 0; r < 4; ++r)
      af[r] = *(const bf16x8*)(sA + ((wr * 4 + r) * 4 + fq) * 128 + fr * 8);
#pragma unroll
    for (int c = 0; c < 4; ++c) {
      const bf16x8 bf = *(const bf16x8*)(sB + ((wc * 4 + c) * 4 + fq) * 128 + fr * 8);
#pragma unroll
      for (int r = 0; r < 4; ++r)
        acc[r][c] = __builtin_amdgcn_mfma_f32_16x16x32_bf16(af[r], bf, acc[r][c], 0, 0, 0);
    }
  }
  const int rq = fq * 4;
#pragma unroll
  for (int c = 0; c < 4; ++c) {
    const int col = cb * 128 + wc * 64 + c * 16 + fr;
    const float bz = bias[col];
#pragma unroll
    for (int r = 0; r < 4; ++r) {
      const int row0 = rb * 128 + wr * 64 + r * 16 + rq;
#pragma unroll
      for (int g = 0; g < 4; ++g)
        out[(size_t)(row0 + g) * 256 + col] = acc[r][c][g] + bz;
    }
  }
}

// ---------- sampler: 8 queries / 256-thread block ----------
// corner entry packed: row (low 16) | bf16(weight) (high 16)
__global__ __launch_bounds__(256) void msda_sample4(
    const u16* __restrict__ value, const float* __restrict__ off,
    const float* __restrict__ attnl, const float* __restrict__ refp,
    u16* __restrict__ samp) {
  __shared__ float s_aw[64 * 17];
  __shared__ uint4 s_ent[16 * 64];
  const int t = threadIdx.x;
  // XCD swizzle: contiguous 680-block (5440-query) range per XCD
  const int bid = (blockIdx.x & 7) * 680 + (blockIdx.x >> 3);
  const int bq0 = bid * 8;

  if (t < 64) {
    const float* lg = attnl + (size_t)(bq0 + (t >> 3)) * 128 + (t & 7) * 16;
    float e[16];
    float m = -1e30f;
#pragma unroll
    for (int i = 0; i < 16; ++i) {
      e[i] = lg[i];
      m = fmaxf(m, e[i]);
    }
    float s = 0.f;
#pragma unroll
    for (int i = 0; i < 16; ++i) {
      e[i] = __expf(e[i] - m);
      s += e[i];
    }
    const float inv = 1.f / s;
#pragma unroll
    for (int i = 0; i < 16; ++i) s_aw[t * 17 + i] = e[i] * inv;
  }
  __syncthreads();

#pragma unroll
  for (int rr = 0; rr < 4; ++rr) {
    const int id = t + rr * 256;
    const int qh = id & 63, lp = id >> 6;
    const int q = qh >> 3, h = qh & 7, lv = lp >> 2, p = lp & 3;
    const int bq = bq0 + q;
    const int Wl = 128 >> lv;
    const int st = (lv == 0) ? 0 : (lv == 1) ? 16384 : (lv == 2) ? 20480 : 21504;
    const float ox = off[(size_t)bq * 256 + ((h * 4 + lv) * 4 + p) * 2];
    const float oy = off[(size_t)bq * 256 + ((h * 4 + lv) * 4 + p) * 2 + 1];
    const float rx = refp[(size_t)bq * 8 + lv * 2];
    const float ry = refp[(size_t)bq * 8 + lv * 2 + 1];
    const float aw = s_aw[qh * 17 + lp];
    const float x = rx * (float)Wl + ox - 0.5f;
    const float y = ry * (float)Wl + oy - 0.5f;
    const float xf = floorf(x), yf = floorf(y);
    const int x0 = (int)xf, y0 = (int)yf;
    const float lw = x - xf, lh = y - yf;
    const float hw = 1.f - lw, hh = 1.f - lh;
    const int ixs[4] = {x0, x0 + 1, x0, x0 + 1};
    const int iys[4] = {y0, y0, y0 + 1, y0 + 1};
    const float wts[4] = {hw * hh, lw * hh, hw * lh, lw * lh};
    u32 ent[4];
#pragma unroll
    for (int c = 0; c < 4; ++c) {
      const int ix = ixs[c], iy = iys[c];
      const bool valid = (ix >= 0) & (ix < Wl) & (iy >= 0) & (iy < Wl);
      int idx = iy * Wl + ix;
      idx = max(0, min(idx, Wl * Wl - 1));
      const float w = valid ? (wts[c] * aw) : 0.f;
      ent[c] = (u32)(st + idx) | ((u32)f2bf(w) << 16);
    }
    uint4 ev;
    ev.x = ent[0];
    ev.y = ent[1];
    ev.z = ent[2];
    ev.w = ent[3];
    s_ent[lp * 64 + qh] = ev;
  }
  __syncthreads();

  const int q = t >> 5, h = (t >> 2) & 7, dg = t & 3;
  const int qh = q * 8 + h;
  const int bq = bq0 + q;
  const u16* vp = value + (size_t)((bq >= LQ_) ? LIN_ : 0) * CDIM + h * 32 + dg * 8;
  float a0 = 0.f, a1 = 0.f, a2 = 0.f, a3 = 0.f;
  float a4 = 0.f, a5 = 0.f, a6 = 0.f, a7 = 0.f;
#pragma unroll 4
  for (int lp = 0; lp < 16; ++lp) {
    const uint4 ev = s_ent[lp * 64 + qh];
    const u32 es[4] = {ev.x, ev.y, ev.z, ev.w};
#pragma unroll
    for (int c = 0; c < 4; ++c) {
      const u32 e = es[c];
      const float w = bfhi(e);
      const uint4 d = *(const uint4*)(vp + (size_t)(e & 0xffffu) * CDIM);
      a0 += w * bflo(d.x);
      a1 += w * bfhi(d.x);
      a2 += w * bflo(d.y);
      a3 += w * bfhi(d.y);
      a4 += w * bflo(d.z);
      a5 += w * bfhi(d.z);
      a6 += w * bflo(d.w);
      a7 += w * bfhi(d.w);
    }
  }
  uint4 o;
  o.x = pack_bf16_rne(a0, a1);
  o.y = pack_bf16_rne(a2, a3);
  o.z = pack_bf16_rne(a4, a5);
  o.w = pack_bf16_rne(a6, a7);
  // store directly in frag-tile layout for gemm_out: tile=(bq>>7)*8+h,
  // c2=((bq&127)>>4)*4+dg, subrow=bq&15
  const int tile = (bq >> 7) * 8 + h;
  const int c2 = ((bq & 127) >> 4) * 4 + dg;
  *(uint4*)(samp + ((size_t)tile * 512 + c2 * 16 + (bq & 15)) * 8) = o;
}

extern "C" void kernel_launch(void* const* d_in, const int* in_sizes, int n_in,
                              void* d_out, int out_size, void* d_ws, size_t ws_size,
                              hipStream_t stream) {
  const float* query = (const float*)d_in[0];
  const float* refp = (const float*)d_in[1];
  const float* inflat = (const float*)d_in[2];
  const float* Wv = (const float*)d_in[3];
  const float* bv = (const float*)d_in[4];
  const float* Wof = (const float*)d_in[5];
  const float* bof = (const float*)d_in[6];
  const float* Wa = (const float*)d_in[7];
  const float* ba = (const float*)d_in[8];
  const float* Wo = (const float*)d_in[9];
  const float* bo = (const float*)d_in[10];
  float* out = (float*)d_out;

  const size_t M = MROWS;

  u16* If = (u16*)d_ws;                      // M*256 bf16 frag-tile (reused as samp)
  u16* Qf = If + M * 256;                    // M*256 bf16 frag-tile
  u16* ws_value = Qf + M * 256;              // M*256 bf16 row-major
  float* ws_off = (float*)(ws_value + M * 256);  // M*256 f32
  float* ws_attn = ws_off + M * 256;         // M*128 f32
  u16* WfV = (u16*)(ws_attn + M * 128);      // 256*256 bf16
  u16* WfC = WfV + 256 * 256;                // 256*384 bf16
  u16* WfO = WfC + 384 * 256;                // 256*256 bf16
  float* bcat = (float*)(WfO + 256 * 256);   // 384 f32
  u16* ws_samp = If;                         // alias: If dead after gemm_value

  conv_all<<<dim3(114), dim3(256), 0, stream>>>(Wv, Wof, Wa, Wo, bof, ba, WfV, WfC, WfO,
                                                bcat);
  conv_act<<<dim3(10880), dim3(256), 0, stream>>>(query, inflat, Qf, If);
  gemm_value<<<dim3(680), dim3(256), 0, stream>>>(If, WfV, bv, ws_value);
  gemm_qc<<<dim3(1020), dim3(256), 0, stream>>>(Qf, WfC, bcat, ws_off, ws_attn);
  msda_sample4<<<dim3(5440), dim3(256), 0, stream>>>(ws_value, ws_off, ws_attn, refp,
                                                     ws_samp);
  gemm_out<<<dim3(680), dim3(256), 0, stream>>>(ws_samp, WfO, bo, out);
}

// Round 8
// 315.228 us; speedup vs baseline: 1.0130x; 1.0130x over previous
//
#include <hip/hip_runtime.h>

typedef unsigned short u16;
typedef unsigned int u32;
typedef short bf16x8 __attribute__((ext_vector_type(8)));
typedef float f32x4 __attribute__((ext_vector_type(4)));

#define LQ_ 21760
#define LIN_ 21760
#define CDIM 256
#define MROWS (2 * LQ_)  // 43520

__device__ __forceinline__ u16 f2bf(float f) {
  u32 u;
  __builtin_memcpy(&u, &f, 4);
  u32 r = (u + 0x7fffu + ((u >> 16) & 1u)) >> 16;
  return (u16)r;
}
__device__ __forceinline__ u32 pack_bf16_rne(float a, float b) {
  return (u32)f2bf(a) | ((u32)f2bf(b) << 16);
}
__device__ __forceinline__ float bflo(u32 u) {
  u32 v = u << 16;
  float f;
  __builtin_memcpy(&f, &v, 4);
  return f;
}
__device__ __forceinline__ float bfhi(u32 u) {
  u32 v = u & 0xffff0000u;
  float f;
  __builtin_memcpy(&f, &v, 4);
  return f;
}
// async global->LDS, 16 B per lane; lds dest = wave-uniform base + lane*16
__device__ __forceinline__ void ldst16(const u16* g, u16* l) {
  __builtin_amdgcn_global_load_lds((const __attribute__((address_space(1))) void*)g,
                                   (__attribute__((address_space(3))) void*)l, 16, 0, 0);
}

// ---------- weight pre-conversion to bf16 fragment-chunk layout ----------
// chunkIdx = ks*(N/4) + (n>>4)*4 + ((k>>3)&3); element (n&15)*8 + (k&7).
__device__ __forceinline__ void conv_one(const float* W0, const float* W1, u16* Wf,
                                         int N, int split, int blk, int t) {
  const int tid = blk * 256 + t;
  if (tid >= N * 32) return;
  const int n = tid >> 5, kcg = tid & 31;
  float w[8];
#pragma unroll
  for (int j = 0; j < 8; ++j) {
    const int k = kcg * 8 + j;
    w[j] = (n < split) ? W0[(size_t)k * split + n]
                       : W1[(size_t)k * (N - split) + (n - split)];
  }
  uint4 pk;
  pk.x = pack_bf16_rne(w[0], w[1]);
  pk.y = pack_bf16_rne(w[2], w[3]);
  pk.z = pack_bf16_rne(w[4], w[5]);
  pk.w = pack_bf16_rne(w[6], w[7]);
  const int ks = kcg >> 2, kcr = kcg & 3, c = n >> 4;
  const int chunk = ks * (N / 4) + c * 4 + kcr;
  *(uint4*)(Wf + (size_t)chunk * 128 + (n & 15) * 8) = pk;
}

// ---------- fused pre-conversion: weights (blocks 0..113) + activations ----------
// Activation frag-tile: tile=(row>>7)*8+(k>>5) at tile*4096; chunk
// c2=((row&127)>>4)*4+((k&31)>>3), subrow=row&15. Linear uint4 j:
// tile=j>>9, c2=(j>>4)&31, sr=j&15.
__global__ __launch_bounds__(256) void conv_fused(
    const float* __restrict__ Wv, const float* __restrict__ Wof,
    const float* __restrict__ Wa, const float* __restrict__ Wo,
    const float* __restrict__ bof, const float* __restrict__ ba,
    u16* __restrict__ WfV, u16* __restrict__ WfC, u16* __restrict__ WfO,
    float* __restrict__ bcat, const float* __restrict__ Aq,
    const float* __restrict__ Ai, u16* __restrict__ Qf, u16* __restrict__ If) {
  const int b = blockIdx.x, t = threadIdx.x;
  if (b < 32) {
    conv_one(Wv, Wv, WfV, 256, 256, b, t);
    return;
  }
  if (b < 80) {
    conv_one(Wof, Wa, WfC, 384, 256, b - 32, t);
    return;
  }
  if (b < 112) {
    conv_one(Wo, Wo, WfO, 256, 256, b - 80, t);
    return;
  }
  if (b < 114) {
    const int i = (b - 112) * 256 + t;
    if (i < 384) bcat[i] = (i < 256) ? bof[i] : ba[i - 256];
    return;
  }
  const int i = (b - 114) * 256 + t;
  const int n4 = MROWS * 32;
  const float* src;
  u16* dst;
  int j;
  if (i < n4) {
    src = Aq;
    dst = Qf;
    j = i;
  } else {
    src = Ai;
    dst = If;
    j = i - n4;
  }
  const int tile = j >> 9;
  const int c2 = (j >> 4) & 31;
  const int sr = j & 15;
  const int row = (tile >> 3) * 128 + (c2 >> 2) * 16 + sr;
  const int kc = (tile & 7) * 32 + (c2 & 3) * 8;
  const float4 f0 = *(const float4*)(src + (size_t)row * 256 + kc);
  const float4 f1 = *(const float4*)(src + (size_t)row * 256 + kc + 4);
  uint4 pk;
  pk.x = pack_bf16_rne(f0.x, f0.y);
  pk.y = pack_bf16_rne(f0.z, f0.w);
  pk.z = pack_bf16_rne(f1.x, f1.y);
  pk.w = pack_bf16_rne(f1.z, f1.w);
  *(uint4*)(dst + (size_t)j * 8) = pk;
}

// ---------- merged GEMM: blocks [0,680) value-proj, [680,1700) off/attn-proj ----------
// 128x128 tile, 4 waves 2x2, BK=32; staging = 4 async 16-B lds loads/thread.
__global__ __launch_bounds__(256) void gemm_vq(
    const u16* __restrict__ If, const u16* __restrict__ WfV,
    const float* __restrict__ bv, u16* __restrict__ outV,
    const u16* __restrict__ Qf, const u16* __restrict__ WfC,
    const float* __restrict__ bcat, float* __restrict__ outO,
    float* __restrict__ outA) {
  __shared__ u16 sA[4096];
  __shared__ u16 sB[4096];
  const int t = threadIdx.x, l = t & 63, wv = t >> 6;
  const int wr = wv >> 1, wc = wv & 1;
  const int fq = l >> 4, fr = l & 15;
  f32x4 acc[4][4];
#pragma unroll
  for (int r = 0; r < 4; ++r)
#pragma unroll
    for (int c = 0; c < 4; ++c) acc[r][c] = f32x4{0.f, 0.f, 0.f, 0.f};

  if (blockIdx.x < 680) {
    const int rb = blockIdx.x >> 1, cb = blockIdx.x & 1;
    for (int ks = 0; ks < 8; ++ks) {
      __syncthreads();
      const u16* ga = If + ((size_t)(rb * 8 + ks)) * 4096 + wv * 1024 + l * 8;
      u16* la = sA + wv * 1024;
      ldst16(ga, la);
      ldst16(ga + 512, la + 512);
      const u16* gb = WfV + ((size_t)(ks * 64 + cb * 32)) * 128 + wv * 1024 + l * 8;
      u16* lb = sB + wv * 1024;
      ldst16(gb, lb);
      ldst16(gb + 512, lb + 512);
      __syncthreads();
      bf16x8 af[4];
#pragma unroll
      for (int r = 0; r < 4; ++r)
        af[r] = *(const bf16x8*)(sA + ((wr * 4 + r) * 4 + fq) * 128 + fr * 8);
#pragma unroll
      for (int c = 0; c < 4; ++c) {
        const bf16x8 bf = *(const bf16x8*)(sB + ((wc * 4 + c) * 4 + fq) * 128 + fr * 8);
#pragma unroll
        for (int r = 0; r < 4; ++r)
          acc[r][c] = __builtin_amdgcn_mfma_f32_16x16x32_bf16(af[r], bf, acc[r][c], 0, 0, 0);
      }
    }
    const int rq = fq * 4;
#pragma unroll
    for (int c = 0; c < 4; ++c) {
      const int col = cb * 128 + wc * 64 + c * 16 + fr;
      const float bz = bv[col];
#pragma unroll
      for (int r = 0; r < 4; ++r) {
        const int row0 = rb * 128 + wr * 64 + r * 16 + rq;
#pragma unroll
        for (int g = 0; g < 4; ++g)
          outV[(size_t)(row0 + g) * 256 + col] = f2bf(acc[r][c][g] + bz);
      }
    }
  } else {
    const int bid = blockIdx.x - 680;
    const int rb = bid / 3, cb = bid % 3;
    for (int ks = 0; ks < 8; ++ks) {
      __syncthreads();
      const u16* ga = Qf + ((size_t)(rb * 8 + ks)) * 4096 + wv * 1024 + l * 8;
      u16* la = sA + wv * 1024;
      ldst16(ga, la);
      ldst16(ga + 512, la + 512);
      const u16* gb = WfC + ((size_t)(ks * 96 + cb * 32)) * 128 + wv * 1024 + l * 8;
      u16* lb = sB + wv * 1024;
      ldst16(gb, lb);
      ldst16(gb + 512, lb + 512);
      __syncthreads();
      bf16x8 af[4];
#pragma unroll
      for (int r = 0; r < 4; ++r)
        af[r] = *(const bf16x8*)(sA + ((wr * 4 + r) * 4 + fq) * 128 + fr * 8);
#pragma unroll
      for (int c = 0; c < 4; ++c) {
        const bf16x8 bf = *(const bf16x8*)(sB + ((wc * 4 + c) * 4 + fq) * 128 + fr * 8);
#pragma unroll
        for (int r = 0; r < 4; ++r)
          acc[r][c] = __builtin_amdgcn_mfma_f32_16x16x32_bf16(af[r], bf, acc[r][c], 0, 0, 0);
      }
    }
    const int rq = fq * 4;
#pragma unroll
    for (int c = 0; c < 4; ++c) {
      const int col = cb * 128 + wc * 64 + c * 16 + fr;
      const float bz = bcat[col];
#pragma unroll
      for (int r = 0; r < 4; ++r) {
        const int row0 = rb * 128 + wr * 64 + r * 16 + rq;
#pragma unroll
        for (int g = 0; g < 4; ++g) {
          const float v = acc[r][c][g] + bz;
          if (col < 256)
            outO[(size_t)(row0 + g) * 256 + col] = v;
          else
            outA[(size_t)(row0 + g) * 128 + (col - 256)] = v;
        }
      }
    }
  }
}

// GEMM 3: out = samp(frag-tile bf16) @ WfO + bo -> f32
__global__ __launch_bounds__(256) void gemm_out(
    const u16* __restrict__ Af, const u16* __restrict__ Wf,
    const float* __restrict__ bias, float* __restrict__ out) {
  __shared__ u16 sA[4096];
  __shared__ u16 sB[4096];
  const int rb = blockIdx.x >> 1, cb = blockIdx.x & 1;
  const int t = threadIdx.x, l = t & 63, wv = t >> 6;
  const int wr = wv >> 1, wc = wv & 1;
  const int fq = l >> 4, fr = l & 15;
  f32x4 acc[4][4];
#pragma unroll
  for (int r = 0; r < 4; ++r)
#pragma unroll
    for (int c = 0; c < 4; ++c) acc[r][c] = f32x4{0.f, 0.f, 0.f, 0.f};
  for (int ks = 0; ks < 8; ++ks) {
    __syncthreads();
    const u16* ga = Af + ((size_t)(rb * 8 + ks)) * 4096 + wv * 1024 + l * 8;
    u16* la = sA + wv * 1024;
    ldst16(ga, la);
    ldst16(ga + 512, la + 512);
    const u16* gb = Wf + ((size_t)(ks * 64 + cb * 32)) * 128 + wv * 1024 + l * 8;
    u16* lb = sB + wv * 1024;
    ldst16(gb, lb);
    ldst16(gb + 512, lb + 512);
    __syncthreads();
    bf16x8 af[4];
#pragma unroll
    for (int r = 0; r < 4; ++r)
      af[r] = *(const bf16x8*)(sA + ((wr * 4 + r) * 4 + fq) * 128 + fr * 8);
#pragma unroll
    for (int c = 0; c < 4; ++c) {
      const bf16x8 bf = *(const bf16x8*)(sB + ((wc * 4 + c) * 4 + fq) * 128 + fr * 8);
#pragma unroll
      for (int r = 0; r < 4; ++r)
        acc[r][c] = __builtin_amdgcn_mfma_f32_16x16x32_bf16(af[r], bf, acc[r][c], 0, 0, 0);
    }
  }
  const int rq = fq * 4;
#pragma unroll
  for (int c = 0; c < 4; ++c) {
    const int col = cb * 128 + wc * 64 + c * 16 + fr;
    const float bz = bias[col];
#pragma unroll
    for (int r = 0; r < 4; ++r) {
      const int row0 = rb * 128 + wr * 64 + r * 16 + rq;
#pragma unroll
      for (int g = 0; g < 4; ++g)
        out[(size_t)(row0 + g) * 256 + col] = acc[r][c][g] + bz;
    }
  }
}

// ---------- sampler: 8 queries / 256-thread block, natural block order ----------
// corner entry packed: row (low 16) | bf16(weight) (high 16)
__global__ __launch_bounds__(256) void msda_sample4(
    const u16* __restrict__ value, const float* __restrict__ off,
    const float* __restrict__ attnl, const float* __restrict__ refp,
    u16* __restrict__ samp) {
  __shared__ float s_aw[64 * 17];
  __shared__ uint4 s_ent[16 * 64];
  const int t = threadIdx.x;
  const int bq0 = blockIdx.x * 8;

  if (t < 64) {
    const float* lg = attnl + (size_t)(bq0 + (t >> 3)) * 128 + (t & 7) * 16;
    float e[16];
    float m = -1e30f;
#pragma unroll
    for (int i = 0; i < 16; ++i) {
      e[i] = lg[i];
      m = fmaxf(m, e[i]);
    }
    float s = 0.f;
#pragma unroll
    for (int i = 0; i < 16; ++i) {
      e[i] = __expf(e[i] - m);
      s += e[i];
    }
    const float inv = 1.f / s;
#pragma unroll
    for (int i = 0; i < 16; ++i) s_aw[t * 17 + i] = e[i] * inv;
  }
  __syncthreads();

#pragma unroll
  for (int rr = 0; rr < 4; ++rr) {
    const int id = t + rr * 256;
    const int qh = id & 63, lp = id >> 6;
    const int q = qh >> 3, h = qh & 7, lv = lp >> 2, p = lp & 3;
    const int bq = bq0 + q;
    const int Wl = 128 >> lv;
    const int st = (lv == 0) ? 0 : (lv == 1) ? 16384 : (lv == 2) ? 20480 : 21504;
    const float ox = off[(size_t)bq * 256 + ((h * 4 + lv) * 4 + p) * 2];
    const float oy = off[(size_t)bq * 256 + ((h * 4 + lv) * 4 + p) * 2 + 1];
    const float rx = refp[(size_t)bq * 8 + lv * 2];
    const float ry = refp[(size_t)bq * 8 + lv * 2 + 1];
    const float aw = s_aw[qh * 17 + lp];
    const float x = rx * (float)Wl + ox - 0.5f;
    const float y = ry * (float)Wl + oy - 0.5f;
    const float xf = floorf(x), yf = floorf(y);
    const int x0 = (int)xf, y0 = (int)yf;
    const float lw = x - xf, lh = y - yf;
    const float hw = 1.f - lw, hh = 1.f - lh;
    const int ixs[4] = {x0, x0 + 1, x0, x0 + 1};
    const int iys[4] = {y0, y0, y0 + 1, y0 + 1};
    const float wts[4] = {hw * hh, lw * hh, hw * lh, lw * lh};
    u32 ent[4];
#pragma unroll
    for (int c = 0; c < 4; ++c) {
      const int ix = ixs[c], iy = iys[c];
      const bool valid = (ix >= 0) & (ix < Wl) & (iy >= 0) & (iy < Wl);
      int idx = iy * Wl + ix;
      idx = max(0, min(idx, Wl * Wl - 1));
      const float w = valid ? (wts[c] * aw) : 0.f;
      ent[c] = (u32)(st + idx) | ((u32)f2bf(w) << 16);
    }
    uint4 ev;
    ev.x = ent[0];
    ev.y = ent[1];
    ev.z = ent[2];
    ev.w = ent[3];
    s_ent[lp * 64 + qh] = ev;
  }
  __syncthreads();

  const int q = t >> 5, h = (t >> 2) & 7, dg = t & 3;
  const int qh = q * 8 + h;
  const int bq = bq0 + q;
  const u16* vp = value + (size_t)((bq >= LQ_) ? LIN_ : 0) * CDIM + h * 32 + dg * 8;
  float a0 = 0.f, a1 = 0.f, a2 = 0.f, a3 = 0.f;
  float a4 = 0.f, a5 = 0.f, a6 = 0.f, a7 = 0.f;
#pragma unroll 4
  for (int lp = 0; lp < 16; ++lp) {
    const uint4 ev = s_ent[lp * 64 + qh];
    const u32 es[4] = {ev.x, ev.y, ev.z, ev.w};
#pragma unroll
    for (int c = 0; c < 4; ++c) {
      const u32 e = es[c];
      const float w = bfhi(e);
      const uint4 d = *(const uint4*)(vp + (size_t)(e & 0xffffu) * CDIM);
      a0 += w * bflo(d.x);
      a1 += w * bfhi(d.x);
      a2 += w * bflo(d.y);
      a3 += w * bfhi(d.y);
      a4 += w * bflo(d.z);
      a5 += w * bfhi(d.z);
      a6 += w * bflo(d.w);
      a7 += w * bfhi(d.w);
    }
  }
  uint4 o;
  o.x = pack_bf16_rne(a0, a1);
  o.y = pack_bf16_rne(a2, a3);
  o.z = pack_bf16_rne(a4, a5);
  o.w = pack_bf16_rne(a6, a7);
  // store directly in frag-tile layout for gemm_out
  const int tile = (bq >> 7) * 8 + h;
  const int c2 = ((bq & 127) >> 4) * 4 + dg;
  *(uint4*)(samp + ((size_t)tile * 512 + c2 * 16 + (bq & 15)) * 8) = o;
}

extern "C" void kernel_launch(void* const* d_in, const int* in_sizes, int n_in,
                              void* d_out, int out_size, void* d_ws, size_t ws_size,
                              hipStream_t stream) {
  const float* query = (const float*)d_in[0];
  const float* refp = (const float*)d_in[1];
  const float* inflat = (const float*)d_in[2];
  const float* Wv = (const float*)d_in[3];
  const float* bv = (const float*)d_in[4];
  const float* Wof = (const float*)d_in[5];
  const float* bof = (const float*)d_in[6];
  const float* Wa = (const float*)d_in[7];
  const float* ba = (const float*)d_in[8];
  const float* Wo = (const float*)d_in[9];
  const float* bo = (const float*)d_in[10];
  float* out = (float*)d_out;

  const size_t M = MROWS;

  u16* If = (u16*)d_ws;                          // M*256 bf16 frag-tile (reused as samp)
  u16* Qf = If + M * 256;                        // M*256 bf16 frag-tile
  u16* ws_value = Qf + M * 256;                  // M*256 bf16 row-major
  float* ws_off = (float*)(ws_value + M * 256);  // M*256 f32
  float* ws_attn = ws_off + M * 256;             // M*128 f32
  u16* WfV = (u16*)(ws_attn + M * 128);          // 256*256 bf16
  u16* WfC = WfV + 256 * 256;                    // 256*384 bf16
  u16* WfO = WfC + 384 * 256;                    // 256*256 bf16
  float* bcat = (float*)(WfO + 256 * 256);       // 384 f32
  u16* ws_samp = If;                             // alias: If dead after gemm_vq

  conv_fused<<<dim3(10994), dim3(256), 0, stream>>>(Wv, Wof, Wa, Wo, bof, ba, WfV, WfC,
                                                    WfO, bcat, query, inflat, Qf, If);
  gemm_vq<<<dim3(1700), dim3(256), 0, stream>>>(If, WfV, bv, ws_value, Qf, WfC, bcat,
                                                ws_off, ws_attn);
  msda_sample4<<<dim3(5440), dim3(256), 0, stream>>>(ws_value, ws_off, ws_attn, refp,
                                                     ws_samp);
  gemm_out<<<dim3(680), dim3(256), 0, stream>>>(ws_samp, WfO, bo, out);
}

// Round 9
// 296.191 us; speedup vs baseline: 1.0782x; 1.0643x over previous
//
#include <hip/hip_runtime.h>

typedef unsigned short u16;
typedef unsigned int u32;
typedef short bf16x8 __attribute__((ext_vector_type(8)));
typedef float f32x4 __attribute__((ext_vector_type(4)));

#define LQ_ 21760
#define LIN_ 21760
#define CDIM 256
#define MROWS (2 * LQ_)  // 43520

__device__ __forceinline__ u16 f2bf(float f) {
  u32 u;
  __builtin_memcpy(&u, &f, 4);
  u32 r = (u + 0x7fffu + ((u >> 16) & 1u)) >> 16;
  return (u16)r;
}
__device__ __forceinline__ u32 pack_bf16_rne(float a, float b) {
  return (u32)f2bf(a) | ((u32)f2bf(b) << 16);
}
__device__ __forceinline__ float bflo(u32 u) {
  u32 v = u << 16;
  float f;
  __builtin_memcpy(&f, &v, 4);
  return f;
}
__device__ __forceinline__ float bfhi(u32 u) {
  u32 v = u & 0xffff0000u;
  float f;
  __builtin_memcpy(&f, &v, 4);
  return f;
}

// ---------- weight pre-conversion to bf16 fragment-chunk layout ----------
// chunkIdx = ks*(N/4) + (n>>4)*4 + ((k>>3)&3); element (n&15)*8 + (k&7).
__device__ __forceinline__ void conv_one(const float* W0, const float* W1, u16* Wf,
                                         int N, int split, int blk, int t) {
  const int tid = blk * 256 + t;
  if (tid >= N * 32) return;
  const int n = tid >> 5, kcg = tid & 31;
  float w[8];
#pragma unroll
  for (int j = 0; j < 8; ++j) {
    const int k = kcg * 8 + j;
    w[j] = (n < split) ? W0[(size_t)k * split + n]
                       : W1[(size_t)k * (N - split) + (n - split)];
  }
  uint4 pk;
  pk.x = pack_bf16_rne(w[0], w[1]);
  pk.y = pack_bf16_rne(w[2], w[3]);
  pk.z = pack_bf16_rne(w[4], w[5]);
  pk.w = pack_bf16_rne(w[6], w[7]);
  const int ks = kcg >> 2, kcr = kcg & 3, c = n >> 4;
  const int chunk = ks * (N / 4) + c * 4 + kcr;
  *(uint4*)(Wf + (size_t)chunk * 128 + (n & 15) * 8) = pk;
}

// ---------- fused pre-conversion: weights (blocks 0..113) + activations ----------
// Activation frag-tile: tile=(row>>7)*8+(k>>5) at tile*4096; chunk
// c2=((row&127)>>4)*4+((k&31)>>3), subrow=row&15.
__global__ __launch_bounds__(256) void conv_fused(
    const float* __restrict__ Wv, const float* __restrict__ Wof,
    const float* __restrict__ Wa, const float* __restrict__ Wo,
    const float* __restrict__ bof, const float* __restrict__ ba,
    u16* __restrict__ WfV, u16* __restrict__ WfC, u16* __restrict__ WfO,
    float* __restrict__ bcat, const float* __restrict__ Aq,
    const float* __restrict__ Ai, u16* __restrict__ Qf, u16* __restrict__ If) {
  const int b = blockIdx.x, t = threadIdx.x;
  if (b < 32) {
    conv_one(Wv, Wv, WfV, 256, 256, b, t);
    return;
  }
  if (b < 80) {
    conv_one(Wof, Wa, WfC, 384, 256, b - 32, t);
    return;
  }
  if (b < 112) {
    conv_one(Wo, Wo, WfO, 256, 256, b - 80, t);
    return;
  }
  if (b < 114) {
    const int i = (b - 112) * 256 + t;
    if (i < 384) bcat[i] = (i < 256) ? bof[i] : ba[i - 256];
    return;
  }
  const int i = (b - 114) * 256 + t;
  const int n4 = MROWS * 32;
  const float* src;
  u16* dst;
  int j;
  if (i < n4) {
    src = Aq;
    dst = Qf;
    j = i;
  } else {
    src = Ai;
    dst = If;
    j = i - n4;
  }
  const int tile = j >> 9;
  const int c2 = (j >> 4) & 31;
  const int sr = j & 15;
  const int row = (tile >> 3) * 128 + (c2 >> 2) * 16 + sr;
  const int kc = (tile & 7) * 32 + (c2 & 3) * 8;
  const float4 f0 = *(const float4*)(src + (size_t)row * 256 + kc);
  const float4 f1 = *(const float4*)(src + (size_t)row * 256 + kc + 4);
  uint4 pk;
  pk.x = pack_bf16_rne(f0.x, f0.y);
  pk.y = pack_bf16_rne(f0.z, f0.w);
  pk.z = pack_bf16_rne(f1.x, f1.y);
  pk.w = pack_bf16_rne(f1.z, f1.w);
  *(uint4*)(dst + (size_t)j * 8) = pk;
}

// ---------- merged register-direct GEMM (no LDS, no barriers) ----------
// blocks [0,680): value = If @ WfV + bv (bf16 out)
// blocks [680,1700): [off|attn] = Qf @ WfC + bcat (f32 split out)
// Per wave k-step: 4 A-frag + 4 B-frag coalesced 16B/lane loads + 16 MFMA.
__global__ __launch_bounds__(256) void gemm_vq(
    const u16* __restrict__ If, const u16* __restrict__ WfV,
    const float* __restrict__ bv, u16* __restrict__ outV,
    const u16* __restrict__ Qf, const u16* __restrict__ WfC,
    const float* __restrict__ bcat, float* __restrict__ outO,
    float* __restrict__ outA) {
  const int t = threadIdx.x, l = t & 63, wv = t >> 6;
  const int wr = wv >> 1, wc = wv & 1;
  const int fq = l >> 4, fr = l & 15;
  f32x4 acc[4][4];
#pragma unroll
  for (int r = 0; r < 4; ++r)
#pragma unroll
    for (int c = 0; c < 4; ++c) acc[r][c] = f32x4{0.f, 0.f, 0.f, 0.f};

  if (blockIdx.x < 680) {
    const int rb = blockIdx.x >> 1, cb = blockIdx.x & 1;
    // A frag: (rb*8+ks)*4096 + ((wr*4+r)*4+fq)*128 + fr*8
    const u16* ab = If + (size_t)rb * 32768 + (wr * 16 + fq) * 128 + fr * 8;
    // B frag: (ks*64 + (cb*8+wc*4+c)*4 + fq)*128 + fr*8
    const u16* bb = WfV + ((size_t)(cb * 8 + wc * 4) * 4 + fq) * 128 + fr * 8;
#pragma unroll
    for (int ks = 0; ks < 8; ++ks) {
      bf16x8 af[4], bf[4];
#pragma unroll
      for (int r = 0; r < 4; ++r) af[r] = *(const bf16x8*)(ab + ks * 4096 + r * 512);
#pragma unroll
      for (int c = 0; c < 4; ++c) bf[c] = *(const bf16x8*)(bb + ks * 8192 + c * 512);
#pragma unroll
      for (int c = 0; c < 4; ++c)
#pragma unroll
        for (int r = 0; r < 4; ++r)
          acc[r][c] = __builtin_amdgcn_mfma_f32_16x16x32_bf16(af[r], bf[c], acc[r][c], 0, 0, 0);
    }
    const int rq = fq * 4;
#pragma unroll
    for (int c = 0; c < 4; ++c) {
      const int col = cb * 128 + wc * 64 + c * 16 + fr;
      const float bz = bv[col];
#pragma unroll
      for (int r = 0; r < 4; ++r) {
        const int row0 = rb * 128 + wr * 64 + r * 16 + rq;
#pragma unroll
        for (int g = 0; g < 4; ++g)
          outV[(size_t)(row0 + g) * 256 + col] = f2bf(acc[r][c][g] + bz);
      }
    }
  } else {
    const int bid = blockIdx.x - 680;
    const int rb = bid / 3, cb = bid % 3;
    const u16* ab = Qf + (size_t)rb * 32768 + (wr * 16 + fq) * 128 + fr * 8;
    const u16* bb = WfC + ((size_t)(cb * 8 + wc * 4) * 4 + fq) * 128 + fr * 8;
#pragma unroll
    for (int ks = 0; ks < 8; ++ks) {
      bf16x8 af[4], bf[4];
#pragma unroll
      for (int r = 0; r < 4; ++r) af[r] = *(const bf16x8*)(ab + ks * 4096 + r * 512);
#pragma unroll
      for (int c = 0; c < 4; ++c) bf[c] = *(const bf16x8*)(bb + ks * 12288 + c * 512);
#pragma unroll
      for (int c = 0; c < 4; ++c)
#pragma unroll
        for (int r = 0; r < 4; ++r)
          acc[r][c] = __builtin_amdgcn_mfma_f32_16x16x32_bf16(af[r], bf[c], acc[r][c], 0, 0, 0);
    }
    const int rq = fq * 4;
#pragma unroll
    for (int c = 0; c < 4; ++c) {
      const int col = cb * 128 + wc * 64 + c * 16 + fr;
      const float bz = bcat[col];
#pragma unroll
      for (int r = 0; r < 4; ++r) {
        const int row0 = rb * 128 + wr * 64 + r * 16 + rq;
#pragma unroll
        for (int g = 0; g < 4; ++g) {
          const float v = acc[r][c][g] + bz;
          if (col < 256)
            outO[(size_t)(row0 + g) * 256 + col] = v;
          else
            outA[(size_t)(row0 + g) * 128 + (col - 256)] = v;
        }
      }
    }
  }
}

// ---------- GEMM 3: out = samp(row-major bf16) @ WfO + bo -> f32 ----------
// Register-direct; A-frag loads are 16x64B strided (row-major), B coalesced.
__global__ __launch_bounds__(256) void gemm_out(
    const u16* __restrict__ A, const u16* __restrict__ Wf,
    const float* __restrict__ bias, float* __restrict__ out) {
  const int rb = blockIdx.x >> 1, cb = blockIdx.x & 1;
  const int t = threadIdx.x, l = t & 63, wv = t >> 6;
  const int wr = wv >> 1, wc = wv & 1;
  const int fq = l >> 4, fr = l & 15;
  f32x4 acc[4][4];
#pragma unroll
  for (int r = 0; r < 4; ++r)
#pragma unroll
    for (int c = 0; c < 4; ++c) acc[r][c] = f32x4{0.f, 0.f, 0.f, 0.f};
  // A[row][k]: row = rb*128 + wr*64 + r*16 + fr, k = ks*32 + fq*8
  const u16* ab = A + ((size_t)rb * 128 + wr * 64 + fr) * 256 + fq * 8;
  const u16* bb = Wf + ((size_t)(cb * 8 + wc * 4) * 4 + fq) * 128 + fr * 8;
#pragma unroll
  for (int ks = 0; ks < 8; ++ks) {
    bf16x8 af[4], bf[4];
#pragma unroll
    for (int r = 0; r < 4; ++r)
      af[r] = *(const bf16x8*)(ab + (size_t)r * 4096 + ks * 32);
#pragma unroll
    for (int c = 0; c < 4; ++c) bf[c] = *(const bf16x8*)(bb + ks * 8192 + c * 512);
#pragma unroll
    for (int c = 0; c < 4; ++c)
#pragma unroll
      for (int r = 0; r < 4; ++r)
        acc[r][c] = __builtin_amdgcn_mfma_f32_16x16x32_bf16(af[r], bf[c], acc[r][c], 0, 0, 0);
  }
  const int rq = fq * 4;
#pragma unroll
  for (int c = 0; c < 4; ++c) {
    const int col = cb * 128 + wc * 64 + c * 16 + fr;
    const float bz = bias[col];
#pragma unroll
    for (int r = 0; r < 4; ++r) {
      const int row0 = rb * 128 + wr * 64 + r * 16 + rq;
#pragma unroll
      for (int g = 0; g < 4; ++g)
        out[(size_t)(row0 + g) * 256 + col] = acc[r][c][g] + bz;
    }
  }
}

// ---------- sampler: EXACT round-6 configuration (85.7 us measured) ----------
__global__ __launch_bounds__(256) void msda_sample3(
    const u16* __restrict__ value, const float* __restrict__ off,
    const float* __restrict__ attnl, const float* __restrict__ refp,
    u16* __restrict__ out) {
  __shared__ float s_aw[64 * 17];
  __shared__ uint4 s_idx[16 * 64];
  __shared__ float4 s_w[16 * 64];
  const int t = threadIdx.x;
  const int bq0 = blockIdx.x * 8;

  if (t < 64) {
    const float* lg = attnl + (size_t)(bq0 + (t >> 3)) * 128 + (t & 7) * 16;
    float e[16];
    float m = -1e30f;
#pragma unroll
    for (int i = 0; i < 16; ++i) {
      e[i] = lg[i];
      m = fmaxf(m, e[i]);
    }
    float s = 0.f;
#pragma unroll
    for (int i = 0; i < 16; ++i) {
      e[i] = __expf(e[i] - m);
      s += e[i];
    }
    const float inv = 1.f / s;
#pragma unroll
    for (int i = 0; i < 16; ++i) s_aw[t * 17 + i] = e[i] * inv;
  }
  __syncthreads();

#pragma unroll
  for (int rr = 0; rr < 4; ++rr) {
    const int id = t + rr * 256;
    const int qh = id & 63, lp = id >> 6;
    const int q = qh >> 3, h = qh & 7, lv = lp >> 2, p = lp & 3;
    const int bq = bq0 + q;
    const int Wl = 128 >> lv;
    const int st = (lv == 0) ? 0 : (lv == 1) ? 16384 : (lv == 2) ? 20480 : 21504;
    const float ox = off[(size_t)bq * 256 + ((h * 4 + lv) * 4 + p) * 2];
    const float oy = off[(size_t)bq * 256 + ((h * 4 + lv) * 4 + p) * 2 + 1];
    const float rx = refp[(size_t)bq * 8 + lv * 2];
    const float ry = refp[(size_t)bq * 8 + lv * 2 + 1];
    const float aw = s_aw[qh * 17 + lp];
    const float x = rx * (float)Wl + ox - 0.5f;
    const float y = ry * (float)Wl + oy - 0.5f;
    const float xf = floorf(x), yf = floorf(y);
    const int x0 = (int)xf, y0 = (int)yf;
    const float lw = x - xf, lh = y - yf;
    const float hw = 1.f - lw, hh = 1.f - lh;
    const int ixs[4] = {x0, x0 + 1, x0, x0 + 1};
    const int iys[4] = {y0, y0, y0 + 1, y0 + 1};
    const float wts[4] = {hw * hh, lw * hh, hw * lh, lw * lh};
    u32 rows[4];
    float ws4[4];
#pragma unroll
    for (int c = 0; c < 4; ++c) {
      const int ix = ixs[c], iy = iys[c];
      const bool valid = (ix >= 0) & (ix < Wl) & (iy >= 0) & (iy < Wl);
      int idx = iy * Wl + ix;
      idx = max(0, min(idx, Wl * Wl - 1));
      rows[c] = (u32)(st + idx);
      ws4[c] = valid ? (wts[c] * aw) : 0.f;
    }
    uint4 iv;
    iv.x = rows[0];
    iv.y = rows[1];
    iv.z = rows[2];
    iv.w = rows[3];
    s_idx[lp * 64 + qh] = iv;
    s_w[lp * 64 + qh] = make_float4(ws4[0], ws4[1], ws4[2], ws4[3]);
  }
  __syncthreads();

  const int q = t >> 5, h = (t >> 2) & 7, dg = t & 3;
  const int qh = q * 8 + h;
  const int bq = bq0 + q;
  const u16* vp = value + (size_t)((bq >= LQ_) ? LIN_ : 0) * CDIM + h * 32 + dg * 8;
  float a0 = 0.f, a1 = 0.f, a2 = 0.f, a3 = 0.f;
  float a4 = 0.f, a5 = 0.f, a6 = 0.f, a7 = 0.f;
#pragma unroll 4
  for (int lp = 0; lp < 16; ++lp) {
    const uint4 iv = s_idx[lp * 64 + qh];
    const float4 wv = s_w[lp * 64 + qh];
    const u32 rows[4] = {iv.x, iv.y, iv.z, iv.w};
    const float ww[4] = {wv.x, wv.y, wv.z, wv.w};
#pragma unroll
    for (int c = 0; c < 4; ++c) {
      const uint4 d = *(const uint4*)(vp + (size_t)rows[c] * CDIM);
      const float w = ww[c];
      a0 += w * bflo(d.x);
      a1 += w * bfhi(d.x);
      a2 += w * bflo(d.y);
      a3 += w * bfhi(d.y);
      a4 += w * bflo(d.z);
      a5 += w * bfhi(d.z);
      a6 += w * bflo(d.w);
      a7 += w * bfhi(d.w);
    }
  }
  uint4 o;
  o.x = pack_bf16_rne(a0, a1);
  o.y = pack_bf16_rne(a2, a3);
  o.z = pack_bf16_rne(a4, a5);
  o.w = pack_bf16_rne(a6, a7);
  *(uint4*)(out + (size_t)bq * CDIM + h * 32 + dg * 8) = o;
}

extern "C" void kernel_launch(void* const* d_in, const int* in_sizes, int n_in,
                              void* d_out, int out_size, void* d_ws, size_t ws_size,
                              hipStream_t stream) {
  const float* query = (const float*)d_in[0];
  const float* refp = (const float*)d_in[1];
  const float* inflat = (const float*)d_in[2];
  const float* Wv = (const float*)d_in[3];
  const float* bv = (const float*)d_in[4];
  const float* Wof = (const float*)d_in[5];
  const float* bof = (const float*)d_in[6];
  const float* Wa = (const float*)d_in[7];
  const float* ba = (const float*)d_in[8];
  const float* Wo = (const float*)d_in[9];
  const float* bo = (const float*)d_in[10];
  float* out = (float*)d_out;

  const size_t M = MROWS;

  u16* If = (u16*)d_ws;                          // M*256 bf16 frag-tile (reused as samp)
  u16* Qf = If + M * 256;                        // M*256 bf16 frag-tile
  u16* ws_value = Qf + M * 256;                  // M*256 bf16 row-major
  float* ws_off = (float*)(ws_value + M * 256);  // M*256 f32
  float* ws_attn = ws_off + M * 256;             // M*128 f32
  u16* WfV = (u16*)(ws_attn + M * 128);          // 256*256 bf16
  u16* WfC = WfV + 256 * 256;                    // 256*384 bf16
  u16* WfO = WfC + 384 * 256;                    // 256*256 bf16
  float* bcat = (float*)(WfO + 256 * 256);       // 384 f32
  u16* ws_samp = If;                             // alias: If dead after gemm_vq

  conv_fused<<<dim3(10994), dim3(256), 0, stream>>>(Wv, Wof, Wa, Wo, bof, ba, WfV, WfC,
                                                    WfO, bcat, query, inflat, Qf, If);
  gemm_vq<<<dim3(1700), dim3(256), 0, stream>>>(If, WfV, bv, ws_value, Qf, WfC, bcat,
                                                ws_off, ws_attn);
  msda_sample3<<<dim3(5440), dim3(256), 0, stream>>>(ws_value, ws_off, ws_attn, refp,
                                                     ws_samp);
  gemm_out<<<dim3(680), dim3(256), 0, stream>>>(ws_samp, WfO, bo, out);
}

// Round 10
// 287.750 us; speedup vs baseline: 1.1098x; 1.0293x over previous
//
#include <hip/hip_runtime.h>

typedef unsigned short u16;
typedef unsigned int u32;
typedef short bf16x8 __attribute__((ext_vector_type(8)));
typedef float f32x4 __attribute__((ext_vector_type(4)));

#define LQ_ 21760
#define LIN_ 21760
#define CDIM 256
#define MROWS (2 * LQ_)  // 43520

__device__ __forceinline__ u16 f2bf(float f) {
  u32 u;
  __builtin_memcpy(&u, &f, 4);
  u32 r = (u + 0x7fffu + ((u >> 16) & 1u)) >> 16;
  return (u16)r;
}
__device__ __forceinline__ u32 pack_bf16_rne(float a, float b) {
  return (u32)f2bf(a) | ((u32)f2bf(b) << 16);
}
__device__ __forceinline__ float bflo(u32 u) {
  u32 v = u << 16;
  float f;
  __builtin_memcpy(&f, &v, 4);
  return f;
}
__device__ __forceinline__ float bfhi(u32 u) {
  u32 v = u & 0xffff0000u;
  float f;
  __builtin_memcpy(&f, &v, 4);
  return f;
}

// ---------- weight pre-conversion to bf16 fragment-chunk layout ----------
// chunkIdx = ks*(N/4) + (n>>4)*4 + ((k>>3)&3); element (n&15)*8 + (k&7).
__device__ __forceinline__ void conv_one(const float* W0, const float* W1, u16* Wf,
                                         int N, int split, int blk, int t) {
  const int tid = blk * 256 + t;
  if (tid >= N * 32) return;
  const int n = tid >> 5, kcg = tid & 31;
  float w[8];
#pragma unroll
  for (int j = 0; j < 8; ++j) {
    const int k = kcg * 8 + j;
    w[j] = (n < split) ? W0[(size_t)k * split + n]
                       : W1[(size_t)k * (N - split) + (n - split)];
  }
  uint4 pk;
  pk.x = pack_bf16_rne(w[0], w[1]);
  pk.y = pack_bf16_rne(w[2], w[3]);
  pk.z = pack_bf16_rne(w[4], w[5]);
  pk.w = pack_bf16_rne(w[6], w[7]);
  const int ks = kcg >> 2, kcr = kcg & 3, c = n >> 4;
  const int chunk = ks * (N / 4) + c * 4 + kcr;
  *(uint4*)(Wf + (size_t)chunk * 128 + (n & 15) * 8) = pk;
}

// ---------- fused pre-conversion: weights (blocks 0..113) + activations ----------
__global__ __launch_bounds__(256) void conv_fused(
    const float* __restrict__ Wv, const float* __restrict__ Wof,
    const float* __restrict__ Wa, const float* __restrict__ Wo,
    const float* __restrict__ bof, const float* __restrict__ ba,
    u16* __restrict__ WfV, u16* __restrict__ WfC, u16* __restrict__ WfO,
    float* __restrict__ bcat, const float* __restrict__ Aq,
    const float* __restrict__ Ai, u16* __restrict__ Qf, u16* __restrict__ If) {
  const int b = blockIdx.x, t = threadIdx.x;
  if (b < 32) {
    conv_one(Wv, Wv, WfV, 256, 256, b, t);
    return;
  }
  if (b < 80) {
    conv_one(Wof, Wa, WfC, 384, 256, b - 32, t);
    return;
  }
  if (b < 112) {
    conv_one(Wo, Wo, WfO, 256, 256, b - 80, t);
    return;
  }
  if (b < 114) {
    const int i = (b - 112) * 256 + t;
    if (i < 384) bcat[i] = (i < 256) ? bof[i] : ba[i - 256];
    return;
  }
  const int i = (b - 114) * 256 + t;
  const int n4 = MROWS * 32;
  const float* src;
  u16* dst;
  int j;
  if (i < n4) {
    src = Aq;
    dst = Qf;
    j = i;
  } else {
    src = Ai;
    dst = If;
    j = i - n4;
  }
  const int tile = j >> 9;
  const int c2 = (j >> 4) & 31;
  const int sr = j & 15;
  const int row = (tile >> 3) * 128 + (c2 >> 2) * 16 + sr;
  const int kc = (tile & 7) * 32 + (c2 & 3) * 8;
  const float4 f0 = *(const float4*)(src + (size_t)row * 256 + kc);
  const float4 f1 = *(const float4*)(src + (size_t)row * 256 + kc + 4);
  uint4 pk;
  pk.x = pack_bf16_rne(f0.x, f0.y);
  pk.y = pack_bf16_rne(f0.z, f0.w);
  pk.z = pack_bf16_rne(f1.x, f1.y);
  pk.w = pack_bf16_rne(f1.z, f1.w);
  *(uint4*)(dst + (size_t)j * 8) = pk;
}

// ---------- register-direct GEMMs: A panel held in registers, cb loop ----------
// Wave = 64 rows x 64 cols; A panel 64x256 = 32 bf16x8 frags (128 VGPR),
// loaded ONCE; per column-block: stream B frags (L1/L2-hot), 128 MFMAs.
// blocks [0,340): value = If @ WfV + bv (bf16 out, N=256, 2 cb)
// blocks [340,680): [off|attn] = Qf @ WfC + bcat (f32 split, N=384, 3 cb)
__global__ __launch_bounds__(256) void gemm_vq(
    const u16* __restrict__ If, const u16* __restrict__ WfV,
    const float* __restrict__ bv, u16* __restrict__ outV,
    const u16* __restrict__ Qf, const u16* __restrict__ WfC,
    const float* __restrict__ bcat, float* __restrict__ outO,
    float* __restrict__ outA) {
  const int t = threadIdx.x, l = t & 63, wv = t >> 6;
  const int wr = wv >> 1, wc = wv & 1;
  const int fq = l >> 4, fr = l & 15;
  bf16x8 af[8][4];

  if (blockIdx.x < 340) {
    const int rb = blockIdx.x;
    const u16* ab = If + (size_t)rb * 32768 + (wr * 16 + fq) * 128 + fr * 8;
#pragma unroll
    for (int ks = 0; ks < 8; ++ks)
#pragma unroll
      for (int r = 0; r < 4; ++r)
        af[ks][r] = *(const bf16x8*)(ab + ks * 4096 + r * 512);
#pragma unroll
    for (int cb = 0; cb < 2; ++cb) {
      f32x4 acc[4][4];
#pragma unroll
      for (int r = 0; r < 4; ++r)
#pragma unroll
        for (int c = 0; c < 4; ++c) acc[r][c] = f32x4{0.f, 0.f, 0.f, 0.f};
      const u16* bb = WfV + ((size_t)(cb * 8 + wc * 4) * 4 + fq) * 128 + fr * 8;
#pragma unroll
      for (int ks = 0; ks < 8; ++ks) {
        bf16x8 bf[4];
#pragma unroll
        for (int c = 0; c < 4; ++c) bf[c] = *(const bf16x8*)(bb + ks * 8192 + c * 512);
#pragma unroll
        for (int c = 0; c < 4; ++c)
#pragma unroll
          for (int r = 0; r < 4; ++r)
            acc[r][c] = __builtin_amdgcn_mfma_f32_16x16x32_bf16(af[ks][r], bf[c],
                                                                acc[r][c], 0, 0, 0);
      }
      const int rq = fq * 4;
#pragma unroll
      for (int c = 0; c < 4; ++c) {
        const int col = cb * 128 + wc * 64 + c * 16 + fr;
        const float bz = bv[col];
#pragma unroll
        for (int r = 0; r < 4; ++r) {
          const int row0 = rb * 128 + wr * 64 + r * 16 + rq;
#pragma unroll
          for (int g = 0; g < 4; ++g)
            outV[(size_t)(row0 + g) * 256 + col] = f2bf(acc[r][c][g] + bz);
        }
      }
    }
  } else {
    const int rb = blockIdx.x - 340;
    const u16* ab = Qf + (size_t)rb * 32768 + (wr * 16 + fq) * 128 + fr * 8;
#pragma unroll
    for (int ks = 0; ks < 8; ++ks)
#pragma unroll
      for (int r = 0; r < 4; ++r)
        af[ks][r] = *(const bf16x8*)(ab + ks * 4096 + r * 512);
#pragma unroll
    for (int cb = 0; cb < 3; ++cb) {
      f32x4 acc[4][4];
#pragma unroll
      for (int r = 0; r < 4; ++r)
#pragma unroll
        for (int c = 0; c < 4; ++c) acc[r][c] = f32x4{0.f, 0.f, 0.f, 0.f};
      const u16* bb = WfC + ((size_t)(cb * 8 + wc * 4) * 4 + fq) * 128 + fr * 8;
#pragma unroll
      for (int ks = 0; ks < 8; ++ks) {
        bf16x8 bf[4];
#pragma unroll
        for (int c = 0; c < 4; ++c) bf[c] = *(const bf16x8*)(bb + ks * 12288 + c * 512);
#pragma unroll
        for (int c = 0; c < 4; ++c)
#pragma unroll
          for (int r = 0; r < 4; ++r)
            acc[r][c] = __builtin_amdgcn_mfma_f32_16x16x32_bf16(af[ks][r], bf[c],
                                                                acc[r][c], 0, 0, 0);
      }
      const int rq = fq * 4;
#pragma unroll
      for (int c = 0; c < 4; ++c) {
        const int col = cb * 128 + wc * 64 + c * 16 + fr;
        const float bz = bcat[col];
#pragma unroll
        for (int r = 0; r < 4; ++r) {
          const int row0 = rb * 128 + wr * 64 + r * 16 + rq;
#pragma unroll
          for (int g = 0; g < 4; ++g) {
            const float v = acc[r][c][g] + bz;
            if (col < 256)
              outO[(size_t)(row0 + g) * 256 + col] = v;
            else
              outA[(size_t)(row0 + g) * 128 + (col - 256)] = v;
          }
        }
      }
    }
  }
}

// ---------- GEMM 3: out = samp(row-major bf16) @ WfO + bo -> f32 ----------
// A panel in registers (strided row-major frag loads), cb loop over 2 col-blocks.
__global__ __launch_bounds__(256) void gemm_out(
    const u16* __restrict__ A, const u16* __restrict__ Wf,
    const float* __restrict__ bias, float* __restrict__ out) {
  const int rb = blockIdx.x;
  const int t = threadIdx.x, l = t & 63, wv = t >> 6;
  const int wr = wv >> 1, wc = wv & 1;
  const int fq = l >> 4, fr = l & 15;
  bf16x8 af[8][4];
  const u16* ab = A + ((size_t)rb * 128 + wr * 64 + fr) * 256 + fq * 8;
#pragma unroll
  for (int ks = 0; ks < 8; ++ks)
#pragma unroll
    for (int r = 0; r < 4; ++r)
      af[ks][r] = *(const bf16x8*)(ab + (size_t)r * 4096 + ks * 32);
#pragma unroll
  for (int cb = 0; cb < 2; ++cb) {
    f32x4 acc[4][4];
#pragma unroll
    for (int r = 0; r < 4; ++r)
#pragma unroll
      for (int c = 0; c < 4; ++c) acc[r][c] = f32x4{0.f, 0.f, 0.f, 0.f};
    const u16* bb = Wf + ((size_t)(cb * 8 + wc * 4) * 4 + fq) * 128 + fr * 8;
#pragma unroll
    for (int ks = 0; ks < 8; ++ks) {
      bf16x8 bf[4];
#pragma unroll
      for (int c = 0; c < 4; ++c) bf[c] = *(const bf16x8*)(bb + ks * 8192 + c * 512);
#pragma unroll
      for (int c = 0; c < 4; ++c)
#pragma unroll
        for (int r = 0; r < 4; ++r)
          acc[r][c] = __builtin_amdgcn_mfma_f32_16x16x32_bf16(af[ks][r], bf[c],
                                                              acc[r][c], 0, 0, 0);
    }
    const int rq = fq * 4;
#pragma unroll
    for (int c = 0; c < 4; ++c) {
      const int col = cb * 128 + wc * 64 + c * 16 + fr;
      const float bz = bias[col];
#pragma unroll
      for (int r = 0; r < 4; ++r) {
        const int row0 = rb * 128 + wr * 64 + r * 16 + rq;
#pragma unroll
        for (int g = 0; g < 4; ++g)
          out[(size_t)(row0 + g) * 256 + col] = acc[r][c][g] + bz;
      }
    }
  }
}

// ---------- sampler: EXACT round-6/9 configuration (85.8 us measured) ----------
__global__ __launch_bounds__(256) void msda_sample3(
    const u16* __restrict__ value, const float* __restrict__ off,
    const float* __restrict__ attnl, const float* __restrict__ refp,
    u16* __restrict__ out) {
  __shared__ float s_aw[64 * 17];
  __shared__ uint4 s_idx[16 * 64];
  __shared__ float4 s_w[16 * 64];
  const int t = threadIdx.x;
  const int bq0 = blockIdx.x * 8;

  if (t < 64) {
    const float* lg = attnl + (size_t)(bq0 + (t >> 3)) * 128 + (t & 7) * 16;
    float e[16];
    float m = -1e30f;
#pragma unroll
    for (int i = 0; i < 16; ++i) {
      e[i] = lg[i];
      m = fmaxf(m, e[i]);
    }
    float s = 0.f;
#pragma unroll
    for (int i = 0; i < 16; ++i) {
      e[i] = __expf(e[i] - m);
      s += e[i];
    }
    const float inv = 1.f / s;
#pragma unroll
    for (int i = 0; i < 16; ++i) s_aw[t * 17 + i] = e[i] * inv;
  }
  __syncthreads();

#pragma unroll
  for (int rr = 0; rr < 4; ++rr) {
    const int id = t + rr * 256;
    const int qh = id & 63, lp = id >> 6;
    const int q = qh >> 3, h = qh & 7, lv = lp >> 2, p = lp & 3;
    const int bq = bq0 + q;
    const int Wl = 128 >> lv;
    const int st = (lv == 0) ? 0 : (lv == 1) ? 16384 : (lv == 2) ? 20480 : 21504;
    const float ox = off[(size_t)bq * 256 + ((h * 4 + lv) * 4 + p) * 2];
    const float oy = off[(size_t)bq * 256 + ((h * 4 + lv) * 4 + p) * 2 + 1];
    const float rx = refp[(size_t)bq * 8 + lv * 2];
    const float ry = refp[(size_t)bq * 8 + lv * 2 + 1];
    const float aw = s_aw[qh * 17 + lp];
    const float x = rx * (float)Wl + ox - 0.5f;
    const float y = ry * (float)Wl + oy - 0.5f;
    const float xf = floorf(x), yf = floorf(y);
    const int x0 = (int)xf, y0 = (int)yf;
    const float lw = x - xf, lh = y - yf;
    const float hw = 1.f - lw, hh = 1.f - lh;
    const int ixs[4] = {x0, x0 + 1, x0, x0 + 1};
    const int iys[4] = {y0, y0, y0 + 1, y0 + 1};
    const float wts[4] = {hw * hh, lw * hh, hw * lh, lw * lh};
    u32 rows[4];
    float ws4[4];
#pragma unroll
    for (int c = 0; c < 4; ++c) {
      const int ix = ixs[c], iy = iys[c];
      const bool valid = (ix >= 0) & (ix < Wl) & (iy >= 0) & (iy < Wl);
      int idx = iy * Wl + ix;
      idx = max(0, min(idx, Wl * Wl - 1));
      rows[c] = (u32)(st + idx);
      ws4[c] = valid ? (wts[c] * aw) : 0.f;
    }
    uint4 iv;
    iv.x = rows[0];
    iv.y = rows[1];
    iv.z = rows[2];
    iv.w = rows[3];
    s_idx[lp * 64 + qh] = iv;
    s_w[lp * 64 + qh] = make_float4(ws4[0], ws4[1], ws4[2], ws4[3]);
  }
  __syncthreads();

  const int q = t >> 5, h = (t >> 2) & 7, dg = t & 3;
  const int qh = q * 8 + h;
  const int bq = bq0 + q;
  const u16* vp = value + (size_t)((bq >= LQ_) ? LIN_ : 0) * CDIM + h * 32 + dg * 8;
  float a0 = 0.f, a1 = 0.f, a2 = 0.f, a3 = 0.f;
  float a4 = 0.f, a5 = 0.f, a6 = 0.f, a7 = 0.f;
#pragma unroll 4
  for (int lp = 0; lp < 16; ++lp) {
    const uint4 iv = s_idx[lp * 64 + qh];
    const float4 wv = s_w[lp * 64 + qh];
    const u32 rows[4] = {iv.x, iv.y, iv.z, iv.w};
    const float ww[4] = {wv.x, wv.y, wv.z, wv.w};
#pragma unroll
    for (int c = 0; c < 4; ++c) {
      const uint4 d = *(const uint4*)(vp + (size_t)rows[c] * CDIM);
      const float w = ww[c];
      a0 += w * bflo(d.x);
      a1 += w * bfhi(d.x);
      a2 += w * bflo(d.y);
      a3 += w * bfhi(d.y);
      a4 += w * bflo(d.z);
      a5 += w * bfhi(d.z);
      a6 += w * bflo(d.w);
      a7 += w * bfhi(d.w);
    }
  }
  uint4 o;
  o.x = pack_bf16_rne(a0, a1);
  o.y = pack_bf16_rne(a2, a3);
  o.z = pack_bf16_rne(a4, a5);
  o.w = pack_bf16_rne(a6, a7);
  *(uint4*)(out + (size_t)bq * CDIM + h * 32 + dg * 8) = o;
}

extern "C" void kernel_launch(void* const* d_in, const int* in_sizes, int n_in,
                              void* d_out, int out_size, void* d_ws, size_t ws_size,
                              hipStream_t stream) {
  const float* query = (const float*)d_in[0];
  const float* refp = (const float*)d_in[1];
  const float* inflat = (const float*)d_in[2];
  const float* Wv = (const float*)d_in[3];
  const float* bv = (const float*)d_in[4];
  const float* Wof = (const float*)d_in[5];
  const float* bof = (const float*)d_in[6];
  const float* Wa = (const float*)d_in[7];
  const float* ba = (const float*)d_in[8];
  const float* Wo = (const float*)d_in[9];
  const float* bo = (const float*)d_in[10];
  float* out = (float*)d_out;

  const size_t M = MROWS;

  u16* If = (u16*)d_ws;                          // M*256 bf16 frag-tile (reused as samp)
  u16* Qf = If + M * 256;                        // M*256 bf16 frag-tile
  u16* ws_value = Qf + M * 256;                  // M*256 bf16 row-major
  float* ws_off = (float*)(ws_value + M * 256);  // M*256 f32
  float* ws_attn = ws_off + M * 256;             // M*128 f32
  u16* WfV = (u16*)(ws_attn + M * 128);          // 256*256 bf16
  u16* WfC = WfV + 256 * 256;                    // 256*384 bf16
  u16* WfO = WfC + 384 * 256;                    // 256*256 bf16
  float* bcat = (float*)(WfO + 256 * 256);       // 384 f32
  u16* ws_samp = If;                             // alias: If dead after gemm_vq

  conv_fused<<<dim3(10994), dim3(256), 0, stream>>>(Wv, Wof, Wa, Wo, bof, ba, WfV, WfC,
                                                    WfO, bcat, query, inflat, Qf, If);
  gemm_vq<<<dim3(680), dim3(256), 0, stream>>>(If, WfV, bv, ws_value, Qf, WfC, bcat,
                                               ws_off, ws_attn);
  msda_sample3<<<dim3(5440), dim3(256), 0, stream>>>(ws_value, ws_off, ws_attn, refp,
                                                     ws_samp);
  gemm_out<<<dim3(340), dim3(256), 0, stream>>>(ws_samp, WfO, bo, out);
}